// Round 5
// baseline (4339.677 us; speedup 1.0000x reference)
//
#include <hip/hip_runtime.h>
#include <hip/hip_bf16.h>

#define B_ 64
#define H1_ 64
#define W1_ 32
#define Hp 70
#define Wp 35
#define C_ 128
#define NH_ 4
#define HD_ 32
#define WS_ 7
#define SS_ 3
#define NWC_ 5
#define NWIN_ 50
#define NTOK_ 49
#define SCALE_ 0.17677669529663687f

typedef __hip_bfloat16 bf16;

__device__ __forceinline__ float b2f(bf16 v) { return __bfloat162float(v); }

// Inputs fp32, output fp32 (established r0-r4: r1/r2 NaN = fp32-as-bf16 input
// misread; r3/r4 absmax 7.59 = bf16-packed output read back as fp32 words).
// One block per window: gather(+shift,+pad) -> LN1 -> qkv -> 4-head attention
// (rel-pos bias + zone mask + softmax) -> PV -> proj -> +residual -> scatter
// unpadded tokens (fp32) into d_out.
__global__ __launch_bounds__(256) void win_attn(
    const float* __restrict__ x,
    const float* __restrict__ n1g, const float* __restrict__ n1b,
    const float* __restrict__ qkvw, const float* __restrict__ qkvb,
    const float* __restrict__ rpb,
    const float* __restrict__ projw, const float* __restrict__ projb,
    float* __restrict__ x1)                 // = d_out, [64, 2048, 128] fp32
{
    __shared__ char smem[62720];
    bf16* qkv_s = (bf16*)smem;              // [0, 37632)
    char* regionA = smem + 37632;           // union{xs_t bf16[6272], sc f32[2401]}
    bf16* cat_s = (bf16*)(smem + 50176);    // [50176, 62720)

    const int tid = threadIdx.x;
    const int lane = tid & 63, wid = tid >> 6;
    const int bw = blockIdx.x;
    const int b = bw / NWIN_, win = bw % NWIN_;
    const int wr = win / NWC_, wc = win % NWC_;

    // ---- 1. gather + LN1 (one wave per token, 2 channels/lane) ----
    bf16* xs_t = (bf16*)regionA;
    for (int n = wid; n < NTOK_; n += 4) {
        int r = n / WS_, cc = n % WS_;
        int h = (wr*WS_ + r + SS_) % Hp;   // xs[hs] = xn[(hs+SS)%H]
        int w = (wc*WS_ + cc + SS_) % Wp;
        int c0 = lane*2;
        float v0 = 0.f, v1 = 0.f;
        if (h < H1_ && w < W1_) {
            const float* src = x + ((size_t)(b*H1_*W1_ + h*W1_ + w))*C_ + c0;
            v0 = src[0]; v1 = src[1];
        }
        float s = v0 + v1, sq = v0*v0 + v1*v1;
        #pragma unroll
        for (int off = 32; off; off >>= 1) {
            s  += __shfl_xor(s, off);
            sq += __shfl_xor(sq, off);
        }
        float mean = s * (1.f/128.f);
        float var  = sq * (1.f/128.f) - mean*mean;   // biased var (jnp.var)
        float rstd = rsqrtf(var + 1e-5f);
        xs_t[n*C_ + c0]   = __float2bfloat16((v0-mean)*rstd*n1g[c0]   + n1b[c0]);
        xs_t[n*C_ + c0+1] = __float2bfloat16((v1-mean)*rstd*n1g[c0+1] + n1b[c0+1]);
    }
    __syncthreads();

    // ---- 2. qkv = xs_t @ qkv_w + qkv_b (q pre-scaled) ----
    for (int o = tid; o < NTOK_*384; o += 256) {
        int n = o / 384, j = o % 384;
        float acc = qkvb[j];
        const bf16* xr = xs_t + n*C_;
        for (int k = 0; k < C_; ++k)
            acc += b2f(xr[k]) * qkvw[k*384 + j];
        if (j < 128) acc *= SCALE_;     // q scaled by HD^-0.5
        qkv_s[o] = __float2bfloat16(acc);
    }
    __syncthreads();

    // ---- 3. per-head attention ----
    float* sc = (float*)regionA;        // xs_t dead
    for (int hd = 0; hd < NH_; ++hd) {
        for (int o = tid; o < NTOK_*NTOK_; o += 256) {
            int i = o / NTOK_, j = o % NTOK_;
            const bf16* qi = qkv_s + i*384 + hd*HD_;
            const bf16* kj = qkv_s + j*384 + 128 + hd*HD_;
            float acc = 0.f;
            for (int d = 0; d < HD_; ++d) acc += b2f(qi[d]) * b2f(kj[d]);
            int ri = i / WS_, ci = i % WS_, rj = j / WS_, cj = j % WS_;
            acc += rpb[((ri - rj + 6)*13 + (ci - cj + 6))*NH_ + hd];
            // zone mask at shifted-image coordinates
            int hi = wr*WS_ + ri, wi = wc*WS_ + ci;
            int hj = wr*WS_ + rj, wj = wc*WS_ + cj;
            int zi = (hi < 63 ? 0 : (hi < 67 ? 1 : 2))*3 + (wi < 28 ? 0 : (wi < 32 ? 1 : 2));
            int zj = (hj < 63 ? 0 : (hj < 67 ? 1 : 2))*3 + (wj < 28 ? 0 : (wj < 32 ? 1 : 2));
            if (zi != zj) acc -= 100.f;
            sc[o] = acc;
        }
        __syncthreads();
        // softmax per row (thread-per-row)
        if (tid < NTOK_) {
            float* row = sc + tid*NTOK_;
            float m = row[0];
            for (int j = 1; j < NTOK_; ++j) m = fmaxf(m, row[j]);
            float ssum = 0.f;
            for (int j = 0; j < NTOK_; ++j) { float e = __expf(row[j] - m); row[j] = e; ssum += e; }
            float inv = 1.f / ssum;
            for (int j = 0; j < NTOK_; ++j) row[j] *= inv;
        }
        __syncthreads();
        // out_head = P @ v -> concat
        for (int o = tid; o < NTOK_*HD_; o += 256) {
            int i = o / HD_, d = o % HD_;
            float acc = 0.f;
            const float* pr = sc + i*NTOK_;
            for (int j = 0; j < NTOK_; ++j)
                acc += pr[j] * b2f(qkv_s[j*384 + 256 + hd*HD_ + d]);
            cat_s[i*C_ + hd*HD_ + d] = __float2bfloat16(acc);
        }
        __syncthreads();
    }

    // ---- 4. proj + residual, scatter unpadded tokens (reverse shift) ----
    for (int o = tid; o < NTOK_*C_; o += 256) {
        int n = o / C_, c = o % C_;
        float acc = projb[c];
        const bf16* ar = cat_s + n*C_;
        for (int k = 0; k < C_; ++k) acc += b2f(ar[k]) * projw[k*C_ + c];
        int r = n / WS_, cc = n % WS_;
        int hh = (wr*WS_ + r + SS_) % Hp;   // window pos -> final image pos
        int ww = (wc*WS_ + cc + SS_) % Wp;
        if (hh < H1_ && ww < W1_) {
            size_t idx = ((size_t)(b*H1_*W1_ + hh*W1_ + ww))*C_ + c;
            x1[idx] = x[idx] + acc;
        }
    }
}

// One block per unpadded token: LN2 -> fc1 + exact GELU -> fc2 -> +residual,
// in place on d_out (fp32). Each thread touches only its own channel in
// global; cross-thread data flows through LDS behind barriers.
__global__ __launch_bounds__(128) void mlp_k(
    float* __restrict__ xio,
    const float* __restrict__ n2g, const float* __restrict__ n2b,
    const float* __restrict__ fc1w, const float* __restrict__ fc1b,
    const float* __restrict__ fc2w, const float* __restrict__ fc2b)
{
    __shared__ float h2[C_];
    __shared__ float hv[512];
    __shared__ float ps[4];
    const int t = threadIdx.x;
    const int gidx = blockIdx.x;           // b*2048 + h*32 + w
    float v = xio[(size_t)gidx*C_ + t];
    float s = v, sq = v*v;
    #pragma unroll
    for (int off = 32; off; off >>= 1) {
        s  += __shfl_xor(s, off);
        sq += __shfl_xor(sq, off);
    }
    if ((t & 63) == 0) { ps[(t>>6)*2] = s; ps[(t>>6)*2+1] = sq; }
    __syncthreads();
    float S = ps[0] + ps[2], SQ = ps[1] + ps[3];
    float mean = S * (1.f/128.f);
    float var  = SQ * (1.f/128.f) - mean*mean;
    float rstd = rsqrtf(var + 1e-5f);
    h2[t] = (v - mean)*rstd*n2g[t] + n2b[t];
    __syncthreads();
    // fc1 + exact GELU (4 hidden cols per thread)
    #pragma unroll
    for (int jj = 0; jj < 4; ++jj) {
        int j = t + jj*128;
        float acc = fc1b[j];
        for (int k = 0; k < C_; ++k) acc += h2[k]*fc1w[k*512 + j];
        hv[j] = acc * 0.5f * (1.f + erff(acc * 0.70710678118654752f));
    }
    __syncthreads();
    // fc2 + residual
    float acc = fc2b[t] + v;
    for (int j = 0; j < 512; ++j) acc += hv[j]*fc2w[j*C_ + t];
    xio[(size_t)gidx*C_ + t] = acc;
}

extern "C" void kernel_launch(void* const* d_in, const int* in_sizes, int n_in,
                              void* d_out, int out_size, void* d_ws, size_t ws_size,
                              hipStream_t stream) {
    const float* x    = (const float*)d_in[0];
    const float* n1g  = (const float*)d_in[1];
    const float* n1b  = (const float*)d_in[2];
    const float* qkvw = (const float*)d_in[3];
    const float* qkvb = (const float*)d_in[4];
    const float* rpb  = (const float*)d_in[5];
    const float* pw   = (const float*)d_in[6];
    const float* pb   = (const float*)d_in[7];
    const float* n2g  = (const float*)d_in[8];
    const float* n2b  = (const float*)d_in[9];
    const float* f1w  = (const float*)d_in[10];
    const float* f1b  = (const float*)d_in[11];
    const float* f2w  = (const float*)d_in[12];
    const float* f2b  = (const float*)d_in[13];

    float* xio = (float*)d_out;   // fp32 residual stream lives in d_out

    hipLaunchKernelGGL(win_attn, dim3(B_*NWIN_), dim3(256), 0, stream,
                       x, n1g, n1b, qkvw, qkvb, rpb, pw, pb, xio);
    hipLaunchKernelGGL(mlp_k, dim3(B_*H1_*W1_), dim3(128), 0, stream,
                       xio, n2g, n2b, f1w, f1b, f2w, f2b);
}

// Round 6
// 733.467 us; speedup vs baseline: 5.9167x; 5.9167x over previous
//
#include <hip/hip_runtime.h>
#include <hip/hip_bf16.h>

#define B_ 64
#define H1_ 64
#define W1_ 32
#define Hp 70
#define Wp 35
#define C_ 128
#define NH_ 4
#define HD_ 32
#define WS_ 7
#define SS_ 3
#define NWC_ 5
#define NWIN_ 50
#define NTOK_ 49
#define SCALE_ 0.17677669529663687f

typedef __hip_bfloat16 bf16;
typedef __attribute__((ext_vector_type(8))) short sh8;     // 8 bf16 = 4 VGPR
typedef __attribute__((ext_vector_type(4))) float f32x4;   // MFMA acc

__device__ __forceinline__ float bs2f(short s) {
    unsigned int u = ((unsigned int)(unsigned short)s) << 16;
    float f; __builtin_memcpy(&f, &u, 4); return f;
}
__device__ __forceinline__ short f2bs(float f) {
    bf16 h = __float2bfloat16(f);
    return *reinterpret_cast<short*>(&h);
}

// ---- prep: fp32 weights -> bf16, transposed to [N][K] for MFMA B-fragments ----
// ws layout (shorts): wq=qkvt[384][128] @0 ; wp=projt[128][128] @49152 ;
//                     w1=fc1t[512][128] @65536 ; w2=fc2t[128][512] @131072
__global__ void prep_k(const float* __restrict__ qkvw, const float* __restrict__ projw,
                       const float* __restrict__ f1w, const float* __restrict__ f2w,
                       short* __restrict__ ws) {
    int tid = blockIdx.x * 256 + threadIdx.x;          // 768*256 = 196608 total
    if (tid < 49152) {
        int n = tid >> 7, k = tid & 127;               // qkv_w [128][384]
        ws[tid] = f2bs(qkvw[k*384 + n]);
    } else if (tid < 65536) {
        int t = tid - 49152; int n = t >> 7, k = t & 127;   // proj_w [128][128]
        ws[tid] = f2bs(projw[k*128 + n]);
    } else if (tid < 131072) {
        int t = tid - 65536; int n = t >> 7, k = t & 127;   // fc1_w [128][512]
        ws[tid] = f2bs(f1w[k*512 + n]);
    } else if (tid < 196608) {
        int t = tid - 131072; int n = t >> 9, k = t & 511;  // fc2_w [512][128]
        ws[tid] = f2bs(f2w[k*128 + n]);
    }
}

// ---- win_attn: gather+LN1 -> MFMA qkv -> VALU attention -> MFMA proj -> residual ----
// LDS map (64800 B):
//   [0,16384)       cat  bf16[64][128]   (16B-aligned A-frag reads for proj)
//   [16384,25992)   regA: union{ xs bf16[32][128] (8192), sc f32[2401] (9604) }
//   [25992,38928)   q_s bf16[49][132]  (pad 132 kills stride-conflicts)
//   [38928,51864)   k_s bf16[49][132]
//   [51864,64800)   v_s bf16[49][132]
__global__ __launch_bounds__(256) void win_attn(
    const float* __restrict__ x,
    const float* __restrict__ n1g, const float* __restrict__ n1b,
    const float* __restrict__ qkvb, const float* __restrict__ rpb,
    const float* __restrict__ projb,
    const short* __restrict__ wq, const short* __restrict__ wp,
    float* __restrict__ out)
{
    __shared__ char smem[64800];
    short* cat  = (short*)smem;
    short* xsp  = (short*)(smem + 16384);
    float* sc   = (float*)(smem + 16384);
    short* q_s  = (short*)(smem + 25992);
    short* k_s  = (short*)(smem + 38928);
    short* v_s  = (short*)(smem + 51864);

    const int tid = threadIdx.x;
    const int lane = tid & 63, wv = tid >> 6;
    const int l15 = lane & 15, l4 = lane >> 4;
    const int bw = blockIdx.x;
    const int b = bw / NWIN_, win = bw % NWIN_;
    const int wr = win / NWC_, wc = win % NWC_;

    // ---- qkv in 2 passes of 32 token-rows (xs buffer is [32][128]) ----
    #pragma unroll
    for (int pass = 0; pass < 2; ++pass) {
        const int t0 = pass * 32;
        const int cnt = pass ? (NTOK_ - 32) : 32;
        // gather + LN1 into xs (one wave per token, 2 ch/lane)
        for (int n = wv; n < cnt; n += 4) {
            int gtok = t0 + n;
            int r = gtok / WS_, cc = gtok % WS_;
            int h = (wr*WS_ + r + SS_) % Hp;
            int w = (wc*WS_ + cc + SS_) % Wp;
            int c0 = lane*2;
            float v0 = 0.f, v1 = 0.f;
            if (h < H1_ && w < W1_) {
                const float* src = x + ((size_t)(b*H1_*W1_ + h*W1_ + w))*C_ + c0;
                v0 = src[0]; v1 = src[1];
            }
            float s = v0 + v1, sq = v0*v0 + v1*v1;
            #pragma unroll
            for (int off = 32; off; off >>= 1) {
                s  += __shfl_xor(s, off);
                sq += __shfl_xor(sq, off);
            }
            float mean = s * (1.f/128.f);
            float var  = sq * (1.f/128.f) - mean*mean;
            float rstd = rsqrtf(var + 1e-5f);
            xsp[n*C_ + c0]   = f2bs((v0-mean)*rstd*n1g[c0]   + n1b[c0]);
            xsp[n*C_ + c0+1] = f2bs((v1-mean)*rstd*n1g[c0+1] + n1b[c0+1]);
        }
        __syncthreads();

        // A-fragments for this pass's 32 rows (2 m-tiles x 4 k-steps)
        sh8 a[2][4];
        #pragma unroll
        for (int m = 0; m < 2; ++m)
            #pragma unroll
            for (int kk = 0; kk < 4; ++kk)
                a[m][kk] = *(const sh8*)(xsp + (m*16 + l15)*C_ + kk*32 + l4*8);

        // each wave: 6 n-tiles of the 24 (384 cols)
        for (int t = 0; t < 6; ++t) {
            int nt = wv*6 + t;
            int n0 = nt*16 + l15;                 // global qkv col 0..383
            f32x4 acc0 = {0.f,0.f,0.f,0.f}, acc1 = {0.f,0.f,0.f,0.f};
            #pragma unroll
            for (int kk = 0; kk < 4; ++kk) {
                sh8 bb = *(const sh8*)(wq + n0*C_ + kk*32 + l4*8);
                acc0 = __builtin_amdgcn_mfma_f32_16x16x32_bf16(a[0][kk], bb, acc0, 0,0,0);
                acc1 = __builtin_amdgcn_mfma_f32_16x16x32_bf16(a[1][kk], bb, acc1, 0,0,0);
            }
            int mat = n0 >> 7, c = n0 & 127;
            short* dst = (mat == 0) ? q_s : (mat == 1) ? k_s : v_s;
            float bias = qkvb[n0];
            float scl = (mat == 0) ? SCALE_ : 1.f;
            #pragma unroll
            for (int r = 0; r < 4; ++r) {
                int m0 = t0 + l4*4 + r;
                if (m0 < NTOK_)      dst[m0*132 + c] = f2bs((acc0[r] + bias) * scl);
                int m1 = t0 + 16 + l4*4 + r;
                if (m1 < NTOK_)      dst[m1*132 + c] = f2bs((acc1[r] + bias) * scl);
            }
        }
        __syncthreads();
    }

    // ---- attention (VALU core, verified r5 logic; padded LDS) ----
    for (int hd = 0; hd < NH_; ++hd) {
        for (int o = tid; o < NTOK_*NTOK_; o += 256) {
            int i = o / NTOK_, j = o % NTOK_;
            const short* qi = q_s + i*132 + hd*HD_;
            const short* kj = k_s + j*132 + hd*HD_;
            float acc = 0.f;
            for (int d = 0; d < HD_; ++d) acc += bs2f(qi[d]) * bs2f(kj[d]);
            int ri = i / WS_, ci = i % WS_, rj = j / WS_, cj = j % WS_;
            acc += rpb[((ri - rj + 6)*13 + (ci - cj + 6))*NH_ + hd];
            int hi = wr*WS_ + ri, wi = wc*WS_ + ci;
            int hj = wr*WS_ + rj, wj = wc*WS_ + cj;
            int zi = (hi < 63 ? 0 : (hi < 67 ? 1 : 2))*3 + (wi < 28 ? 0 : (wi < 32 ? 1 : 2));
            int zj = (hj < 63 ? 0 : (hj < 67 ? 1 : 2))*3 + (wj < 28 ? 0 : (wj < 32 ? 1 : 2));
            if (zi != zj) acc -= 100.f;
            sc[o] = acc;
        }
        __syncthreads();
        if (tid < NTOK_) {
            float* row = sc + tid*NTOK_;
            float m = row[0];
            for (int j = 1; j < NTOK_; ++j) m = fmaxf(m, row[j]);
            float ssum = 0.f;
            for (int j = 0; j < NTOK_; ++j) { float e = __expf(row[j] - m); row[j] = e; ssum += e; }
            float inv = 1.f / ssum;
            for (int j = 0; j < NTOK_; ++j) row[j] *= inv;
        }
        __syncthreads();
        for (int o = tid; o < NTOK_*HD_; o += 256) {
            int i = o / HD_, d = o % HD_;
            float acc = 0.f;
            const float* pr = sc + i*NTOK_;
            for (int j = 0; j < NTOK_; ++j)
                acc += pr[j] * bs2f(v_s[j*132 + hd*HD_ + d]);
            cat[i*C_ + hd*HD_ + d] = f2bs(acc);
        }
        __syncthreads();
    }

    // ---- proj (MFMA) + residual + scatter ----
    // wave = m-tile (16 tokens); 8 n-tiles; K=128 (4 steps)
    {
        sh8 pa[4];
        #pragma unroll
        for (int kk = 0; kk < 4; ++kk)
            pa[kk] = *(const sh8*)(cat + (wv*16 + l15)*C_ + kk*32 + l4*8);
        for (int nt = 0; nt < 8; ++nt) {
            f32x4 acc = {0.f,0.f,0.f,0.f};
            int ch = nt*16 + l15;
            #pragma unroll
            for (int kk = 0; kk < 4; ++kk) {
                sh8 bb = *(const sh8*)(wp + ch*C_ + kk*32 + l4*8);
                acc = __builtin_amdgcn_mfma_f32_16x16x32_bf16(pa[kk], bb, acc, 0,0,0);
            }
            float pb_ = projb[ch];
            #pragma unroll
            for (int r = 0; r < 4; ++r) {
                int m = wv*16 + l4*4 + r;
                if (m < NTOK_) {
                    int rr = m / WS_, cc = m % WS_;
                    int hh = (wr*WS_ + rr + SS_) % Hp;
                    int ww = (wc*WS_ + cc + SS_) % Wp;
                    if (hh < H1_ && ww < W1_) {
                        size_t idx = ((size_t)(b*H1_*W1_ + hh*W1_ + ww))*C_ + ch;
                        out[idx] = x[idx] + acc[r] + pb_;
                    }
                }
            }
        }
    }
}

// ---- mlp: 32 tokens/block, MFMA fc1+GELU+fc2, in place on d_out ----
// LDS: xin f32[32][128] (16384) | h2 bf16[32][136] (8704) | hv bf16[32][520] (33280) = 58368
__global__ __launch_bounds__(256) void mlp_k(
    float* __restrict__ xio,
    const float* __restrict__ n2g, const float* __restrict__ n2b,
    const float* __restrict__ f1b, const float* __restrict__ f2b,
    const short* __restrict__ w1, const short* __restrict__ w2)
{
    __shared__ char smem[58368];
    float* xin = (float*)smem;
    short* h2  = (short*)(smem + 16384);
    short* hv  = (short*)(smem + 16384 + 8704);

    const int tid = threadIdx.x;
    const int lane = tid & 63, wv = tid >> 6;
    const int l15 = lane & 15, l4 = lane >> 4;
    const size_t base = (size_t)blockIdx.x * 32 * C_;

    // stage 32 tokens (fp32, float4-vectorized)
    for (int i = tid; i < 1024; i += 256)
        ((float4*)xin)[i] = ((const float4*)(xio + base))[i];
    __syncthreads();

    // LN2: 8 threads per token
    {
        int tok = tid >> 3, sub = tid & 7;
        float s = 0.f, sq = 0.f;
        #pragma unroll
        for (int c = 0; c < 16; ++c) {
            float v = xin[tok*C_ + sub*16 + c];
            s += v; sq += v*v;
        }
        #pragma unroll
        for (int off = 1; off < 8; off <<= 1) {
            s  += __shfl_xor(s, off);
            sq += __shfl_xor(sq, off);
        }
        float mean = s * (1.f/128.f);
        float var  = sq * (1.f/128.f) - mean*mean;
        float rstd = rsqrtf(var + 1e-5f);
        #pragma unroll
        for (int c = 0; c < 16; ++c) {
            int ch = sub*16 + c;
            h2[tok*136 + ch] = f2bs((xin[tok*C_ + ch] - mean)*rstd*n2g[ch] + n2b[ch]);
        }
    }
    __syncthreads();

    // fc1 + GELU: out [32][512]; wave = (m-tile = wv&1, n-half = wv>>1)
    {
        int mt = wv & 1, nh = wv >> 1;
        sh8 a1[4];
        #pragma unroll
        for (int kk = 0; kk < 4; ++kk)
            a1[kk] = *(const sh8*)(h2 + (mt*16 + l15)*136 + kk*32 + l4*8);
        for (int t = 0; t < 16; ++t) {
            int nt = nh*16 + t;
            int n = nt*16 + l15;               // hidden col 0..511
            f32x4 acc = {0.f,0.f,0.f,0.f};
            #pragma unroll
            for (int kk = 0; kk < 4; ++kk) {
                sh8 bb = *(const sh8*)(w1 + n*C_ + kk*32 + l4*8);
                acc = __builtin_amdgcn_mfma_f32_16x16x32_bf16(a1[kk], bb, acc, 0,0,0);
            }
            float bias = f1b[n];
            #pragma unroll
            for (int r = 0; r < 4; ++r) {
                float xv = acc[r] + bias;
                float g = xv * 0.5f * (1.f + erff(xv * 0.70710678118654752f));
                int m = mt*16 + l4*4 + r;
                hv[m*520 + n] = f2bs(g);
            }
        }
    }
    __syncthreads();

    // fc2: out [32][128]; wave = (m-tile = wv&1, n-tiles (wv>>1)*4 .. +3); K=512 (16 steps)
    {
        int mt = wv & 1, ng = (wv >> 1) * 4;
        f32x4 acc[4] = {{0.f,0.f,0.f,0.f},{0.f,0.f,0.f,0.f},{0.f,0.f,0.f,0.f},{0.f,0.f,0.f,0.f}};
        for (int kk = 0; kk < 16; ++kk) {
            sh8 av = *(const sh8*)(hv + (mt*16 + l15)*520 + kk*32 + l4*8);
            #pragma unroll
            for (int t = 0; t < 4; ++t) {
                sh8 bb = *(const sh8*)(w2 + ((ng + t)*16 + l15)*512 + kk*32 + l4*8);
                acc[t] = __builtin_amdgcn_mfma_f32_16x16x32_bf16(av, bb, acc[t], 0,0,0);
            }
        }
        #pragma unroll
        for (int t = 0; t < 4; ++t) {
            int ch = (ng + t)*16 + l15;
            float bias = f2b[ch];
            #pragma unroll
            for (int r = 0; r < 4; ++r) {
                int m = mt*16 + l4*4 + r;
                xio[base + m*C_ + ch] = xin[m*C_ + ch] + acc[t][r] + bias;
            }
        }
    }
}

extern "C" void kernel_launch(void* const* d_in, const int* in_sizes, int n_in,
                              void* d_out, int out_size, void* d_ws, size_t ws_size,
                              hipStream_t stream) {
    const float* x    = (const float*)d_in[0];
    const float* n1g  = (const float*)d_in[1];
    const float* n1b  = (const float*)d_in[2];
    const float* qkvw = (const float*)d_in[3];
    const float* qkvb = (const float*)d_in[4];
    const float* rpb  = (const float*)d_in[5];
    const float* pw   = (const float*)d_in[6];
    const float* pb   = (const float*)d_in[7];
    const float* n2g  = (const float*)d_in[8];
    const float* n2b  = (const float*)d_in[9];
    const float* f1w  = (const float*)d_in[10];
    const float* f1b  = (const float*)d_in[11];
    const float* f2w  = (const float*)d_in[12];
    const float* f2b  = (const float*)d_in[13];

    short* ws = (short*)d_ws;          // 393216 B of bf16 transposed weights
    const short* wq = ws;
    const short* wp = ws + 49152;
    const short* w1 = ws + 65536;
    const short* w2 = ws + 131072;
    float* xio = (float*)d_out;

    hipLaunchKernelGGL(prep_k, dim3(768), dim3(256), 0, stream, qkvw, pw, f1w, f2w, ws);
    hipLaunchKernelGGL(win_attn, dim3(B_*NWIN_), dim3(256), 0, stream,
                       x, n1g, n1b, qkvb, rpb, pb, wq, wp, xio);
    hipLaunchKernelGGL(mlp_k, dim3(B_*H1_*W1_/32), dim3(256), 0, stream,
                       xio, n2g, n2b, f1b, f2b, w1, w2);
}

// Round 7
// 501.637 us; speedup vs baseline: 8.6510x; 1.4621x over previous
//
#include <hip/hip_runtime.h>
#include <hip/hip_bf16.h>

#define B_ 64
#define H1_ 64
#define W1_ 32
#define Hp 70
#define Wp 35
#define C_ 128
#define NH_ 4
#define HD_ 32
#define WS_ 7
#define SS_ 3
#define NWC_ 5
#define NWIN_ 50
#define NTOK_ 49
#define SCALE_ 0.17677669529663687f

typedef __hip_bfloat16 bf16;
typedef __attribute__((ext_vector_type(8))) short sh8;     // 8 bf16 = 4 VGPR
typedef __attribute__((ext_vector_type(4))) float f32x4;   // MFMA acc

__device__ __forceinline__ float bs2f(short s) {
    unsigned int u = ((unsigned int)(unsigned short)s) << 16;
    float f; __builtin_memcpy(&f, &u, 4); return f;
}
__device__ __forceinline__ short f2bs(float f) {
    bf16 h = __float2bfloat16(f);
    return *reinterpret_cast<short*>(&h);
}

// ---- prep: fp32 weights -> bf16, transposed to [N][K] for MFMA B-fragments ----
__global__ void prep_k(const float* __restrict__ qkvw, const float* __restrict__ projw,
                       const float* __restrict__ f1w, const float* __restrict__ f2w,
                       short* __restrict__ ws) {
    int tid = blockIdx.x * 256 + threadIdx.x;          // 768*256 = 196608 total
    if (tid < 49152) {
        int n = tid >> 7, k = tid & 127;               // qkv_w [128][384]
        ws[tid] = f2bs(qkvw[k*384 + n]);
    } else if (tid < 65536) {
        int t = tid - 49152; int n = t >> 7, k = t & 127;   // proj_w [128][128]
        ws[tid] = f2bs(projw[k*128 + n]);
    } else if (tid < 131072) {
        int t = tid - 65536; int n = t >> 7, k = t & 127;   // fc1_w [128][512]
        ws[tid] = f2bs(f1w[k*512 + n]);
    } else if (tid < 196608) {
        int t = tid - 131072; int n = t >> 9, k = t & 511;  // fc2_w [512][128]
        ws[tid] = f2bs(f2w[k*128 + n]);
    }
}

// ---- win_attn: gather+LN1 -> MFMA qkv -> MFMA attention (wave-parallel
//      softmax, zero-barrier head loop) -> MFMA proj -> residual scatter ----
// LDS map (65168 B):
//   [0,17408)       q_s  bf16[64][136]
//   [17408,34816)   k_s  bf16[64][136]  -> later cat bf16[64][136]
//   [34816,53248)   vt   bf16[128][72]  (V transposed: [ch][tok])
//   [53248,62464)   xs bf16[32][136] (8704, phase A) | p_s bf16[64][72] (9216, phase B)
//   [62464,65168)   rpb_s f32[676]
__global__ __launch_bounds__(256) void win_attn(
    const float* __restrict__ x,
    const float* __restrict__ n1g, const float* __restrict__ n1b,
    const float* __restrict__ qkvb, const float* __restrict__ rpb,
    const float* __restrict__ projb,
    const short* __restrict__ wq, const short* __restrict__ wp,
    float* __restrict__ out)
{
    __shared__ char smem[65168];
    short* q_s  = (short*)smem;
    short* k_s  = (short*)(smem + 17408);
    short* cat  = (short*)(smem + 17408);
    short* vt   = (short*)(smem + 34816);
    short* xsp  = (short*)(smem + 53248);
    short* p_s  = (short*)(smem + 53248);
    float* rpb_s= (float*)(smem + 62464);

    const int tid = threadIdx.x;
    const int lane = tid & 63, wv = tid >> 6;
    const int l15 = lane & 15, l4 = lane >> 4;
    const int bw = blockIdx.x;
    const int b = bw / NWIN_, win = bw % NWIN_;
    const int wr = win / NWC_, wc = win % NWC_;

    // stage rpb (needed in head loop, i.e. after >=1 barrier)
    for (int o = tid; o < 676; o += 256) rpb_s[o] = rpb[o];

    // ---- phase A: qkv in 2 passes of 32 token-rows ----
    #pragma unroll
    for (int pass = 0; pass < 2; ++pass) {
        const int t0 = pass * 32;
        // gather + LN1 into xs; rows >= NTOK_ zero-padded (finite LN of 0)
        for (int n = wv; n < 32; n += 4) {
            int gtok = t0 + n;
            int r = gtok / WS_, cc = gtok % WS_;
            int h = (wr*WS_ + r + SS_) % Hp;
            int w = (wc*WS_ + cc + SS_) % Wp;
            int c0 = lane*2;
            float v0 = 0.f, v1 = 0.f;
            if (gtok < NTOK_ && h < H1_ && w < W1_) {
                const float* src = x + ((size_t)(b*H1_*W1_ + h*W1_ + w))*C_ + c0;
                v0 = src[0]; v1 = src[1];
            }
            float s = v0 + v1, sq = v0*v0 + v1*v1;
            #pragma unroll
            for (int off = 32; off; off >>= 1) {
                s  += __shfl_xor(s, off);
                sq += __shfl_xor(sq, off);
            }
            float mean = s * (1.f/128.f);
            float var  = sq * (1.f/128.f) - mean*mean;
            float rstd = rsqrtf(var + 1e-5f);
            xsp[n*136 + c0]   = f2bs((v0-mean)*rstd*n1g[c0]   + n1b[c0]);
            xsp[n*136 + c0+1] = f2bs((v1-mean)*rstd*n1g[c0+1] + n1b[c0+1]);
        }
        __syncthreads();

        sh8 a[2][4];
        #pragma unroll
        for (int m = 0; m < 2; ++m)
            #pragma unroll
            for (int kk = 0; kk < 4; ++kk)
                a[m][kk] = *(const sh8*)(xsp + (m*16 + l15)*136 + kk*32 + l4*8);

        for (int t = 0; t < 6; ++t) {
            int nt = wv*6 + t;
            int n0 = nt*16 + l15;                 // qkv col 0..383
            f32x4 acc0 = {0.f,0.f,0.f,0.f}, acc1 = {0.f,0.f,0.f,0.f};
            #pragma unroll
            for (int kk = 0; kk < 4; ++kk) {
                sh8 bb = *(const sh8*)(wq + n0*C_ + kk*32 + l4*8);
                acc0 = __builtin_amdgcn_mfma_f32_16x16x32_bf16(a[0][kk], bb, acc0, 0,0,0);
                acc1 = __builtin_amdgcn_mfma_f32_16x16x32_bf16(a[1][kk], bb, acc1, 0,0,0);
            }
            int mat = n0 >> 7, c = n0 & 127;
            float bias = qkvb[n0];
            float scl = (mat == 0) ? SCALE_ : 1.f;
            #pragma unroll
            for (int r = 0; r < 4; ++r) {
                int m0 = t0 + l4*4 + r;
                int m1 = m0 + 16;
                float v0c = (acc0[r] + bias) * scl;
                float v1c = (acc1[r] + bias) * scl;
                if (mat == 0)      { q_s[m0*136 + c] = f2bs(v0c); q_s[m1*136 + c] = f2bs(v1c); }
                else if (mat == 1) { k_s[m0*136 + c] = f2bs(v0c); k_s[m1*136 + c] = f2bs(v1c); }
                else               { vt[c*72 + m0]   = f2bs(v0c); vt[c*72 + m1]   = f2bs(v1c); }
            }
        }
        __syncthreads();
    }

    // ---- phase B: attention; wave wv owns query rows wv*16..wv*16+15 ----
    // precompute per-lane row/col geometry
    int zi_r[4], ri_r[4], ci_r[4]; bool iv[4];
    #pragma unroll
    for (int r = 0; r < 4; ++r) {
        int i = wv*16 + l4*4 + r;
        iv[r] = (i < NTOK_);
        int ri = i / WS_, ci = i % WS_;
        ri_r[r] = ri; ci_r[r] = ci;
        int hi = wr*WS_ + ri, wi = wc*WS_ + ci;
        zi_r[r] = (hi < 63 ? 0 : (hi < 67 ? 1 : 2))*3 + (wi < 28 ? 0 : (wi < 32 ? 1 : 2));
    }
    int zj_n[4], rj_n[4], cj_n[4]; bool jv[4];
    #pragma unroll
    for (int nt = 0; nt < 4; ++nt) {
        int j = nt*16 + l15;
        jv[nt] = (j < NTOK_);
        int rj = j / WS_, cj = j % WS_;
        rj_n[nt] = rj; cj_n[nt] = cj;
        int hj = wr*WS_ + rj, wj = wc*WS_ + cj;
        zj_n[nt] = (hj < 63 ? 0 : (hj < 67 ? 1 : 2))*3 + (wj < 28 ? 0 : (wj < 32 ? 1 : 2));
    }

    f32x4 o_acc[4][2] = {};
    #pragma unroll 1
    for (int h = 0; h < NH_; ++h) {
        // QK^T: 1 k-step (K=32=HD), 4 n-tiles
        sh8 aq = *(const sh8*)(q_s + (wv*16 + l15)*136 + h*HD_ + l4*8);
        f32x4 s[4];
        #pragma unroll
        for (int nt = 0; nt < 4; ++nt) {
            sh8 bk = *(const sh8*)(k_s + (nt*16 + l15)*136 + h*HD_ + l4*8);
            f32x4 z = {0.f,0.f,0.f,0.f};
            s[nt] = __builtin_amdgcn_mfma_f32_16x16x32_bf16(aq, bk, z, 0,0,0);
        }
        // bias + zone mask (overwrite semantics kill any garbage)
        #pragma unroll
        for (int nt = 0; nt < 4; ++nt)
            #pragma unroll
            for (int r = 0; r < 4; ++r) {
                float sv = s[nt][r];
                if (iv[r] && jv[nt]) {
                    sv += rpb_s[((ri_r[r]-rj_n[nt]+6)*13 + (ci_r[r]-cj_n[nt]+6))*4 + h];
                    if (zi_r[r] != zj_n[nt]) sv -= 100.f;
                } else sv = -1e30f;
                s[nt][r] = sv;
            }
        // wave-parallel softmax: row i's 64 cols live in 4 nt x 16 lanes (same l4 group)
        #pragma unroll
        for (int r = 0; r < 4; ++r) {
            float m0 = fmaxf(fmaxf(s[0][r], s[1][r]), fmaxf(s[2][r], s[3][r]));
            #pragma unroll
            for (int off = 1; off < 16; off <<= 1) m0 = fmaxf(m0, __shfl_xor(m0, off));
            float ls = 0.f;
            #pragma unroll
            for (int nt = 0; nt < 4; ++nt) {
                float e = __expf(s[nt][r] - m0);
                s[nt][r] = e; ls += e;
            }
            #pragma unroll
            for (int off = 1; off < 16; off <<= 1) ls += __shfl_xor(ls, off);
            float inv = 1.f / ls;
            #pragma unroll
            for (int nt = 0; nt < 4; ++nt)
                p_s[(wv*16 + l4*4 + r)*72 + nt*16 + l15] = f2bs(s[nt][r] * inv);
        }
        // PV: O[i][d] += P[i][j] * V[j][d]; A = p_s (own rows), B = vt
        sh8 ap0 = *(const sh8*)(p_s + (wv*16 + l15)*72 + l4*8);
        sh8 ap1 = *(const sh8*)(p_s + (wv*16 + l15)*72 + 32 + l4*8);
        #pragma unroll
        for (int nt2 = 0; nt2 < 2; ++nt2) {
            sh8 bv0 = *(const sh8*)(vt + (h*HD_ + nt2*16 + l15)*72 + l4*8);
            sh8 bv1 = *(const sh8*)(vt + (h*HD_ + nt2*16 + l15)*72 + 32 + l4*8);
            o_acc[h][nt2] = __builtin_amdgcn_mfma_f32_16x16x32_bf16(ap0, bv0, o_acc[h][nt2], 0,0,0);
            o_acc[h][nt2] = __builtin_amdgcn_mfma_f32_16x16x32_bf16(ap1, bv1, o_acc[h][nt2], 0,0,0);
        }
    }

    __syncthreads();   // all waves done reading k_s before cat overlays it

    // ---- phase C: O -> cat (own rows), proj MFMA, residual scatter ----
    #pragma unroll
    for (int h = 0; h < NH_; ++h)
        #pragma unroll
        for (int nt2 = 0; nt2 < 2; ++nt2)
            #pragma unroll
            for (int r = 0; r < 4; ++r)
                cat[(wv*16 + l4*4 + r)*136 + h*HD_ + nt2*16 + l15] = f2bs(o_acc[h][nt2][r]);

    sh8 pa[4];
    #pragma unroll
    for (int kk = 0; kk < 4; ++kk)
        pa[kk] = *(const sh8*)(cat + (wv*16 + l15)*136 + kk*32 + l4*8);
    for (int nt = 0; nt < 8; ++nt) {
        f32x4 acc = {0.f,0.f,0.f,0.f};
        int ch = nt*16 + l15;
        #pragma unroll
        for (int kk = 0; kk < 4; ++kk) {
            sh8 bb = *(const sh8*)(wp + ch*C_ + kk*32 + l4*8);
            acc = __builtin_amdgcn_mfma_f32_16x16x32_bf16(pa[kk], bb, acc, 0,0,0);
        }
        float pb_ = projb[ch];
        #pragma unroll
        for (int r = 0; r < 4; ++r) {
            int m = wv*16 + l4*4 + r;
            if (m < NTOK_) {
                int rr = m / WS_, cc = m % WS_;
                int hh = (wr*WS_ + rr + SS_) % Hp;
                int ww = (wc*WS_ + cc + SS_) % Wp;
                if (hh < H1_ && ww < W1_) {
                    size_t idx = ((size_t)(b*H1_*W1_ + hh*W1_ + ww))*C_ + ch;
                    out[idx] = x[idx] + acc[r] + pb_;
                }
            }
        }
    }
}

// ---- mlp: 32 tokens/block, MFMA fc1+GELU+fc2, in place on d_out (unchanged r6) ----
__global__ __launch_bounds__(256) void mlp_k(
    float* __restrict__ xio,
    const float* __restrict__ n2g, const float* __restrict__ n2b,
    const float* __restrict__ f1b, const float* __restrict__ f2b,
    const short* __restrict__ w1, const short* __restrict__ w2)
{
    __shared__ char smem[58368];
    float* xin = (float*)smem;
    short* h2  = (short*)(smem + 16384);
    short* hv  = (short*)(smem + 16384 + 8704);

    const int tid = threadIdx.x;
    const int lane = tid & 63, wv = tid >> 6;
    const int l15 = lane & 15, l4 = lane >> 4;
    const size_t base = (size_t)blockIdx.x * 32 * C_;

    for (int i = tid; i < 1024; i += 256)
        ((float4*)xin)[i] = ((const float4*)(xio + base))[i];
    __syncthreads();

    {
        int tok = tid >> 3, sub = tid & 7;
        float s = 0.f, sq = 0.f;
        #pragma unroll
        for (int c = 0; c < 16; ++c) {
            float v = xin[tok*C_ + sub*16 + c];
            s += v; sq += v*v;
        }
        #pragma unroll
        for (int off = 1; off < 8; off <<= 1) {
            s  += __shfl_xor(s, off);
            sq += __shfl_xor(sq, off);
        }
        float mean = s * (1.f/128.f);
        float var  = sq * (1.f/128.f) - mean*mean;
        float rstd = rsqrtf(var + 1e-5f);
        #pragma unroll
        for (int c = 0; c < 16; ++c) {
            int ch = sub*16 + c;
            h2[tok*136 + ch] = f2bs((xin[tok*C_ + ch] - mean)*rstd*n2g[ch] + n2b[ch]);
        }
    }
    __syncthreads();

    {
        int mt = wv & 1, nh = wv >> 1;
        sh8 a1[4];
        #pragma unroll
        for (int kk = 0; kk < 4; ++kk)
            a1[kk] = *(const sh8*)(h2 + (mt*16 + l15)*136 + kk*32 + l4*8);
        for (int t = 0; t < 16; ++t) {
            int nt = nh*16 + t;
            int n = nt*16 + l15;
            f32x4 acc = {0.f,0.f,0.f,0.f};
            #pragma unroll
            for (int kk = 0; kk < 4; ++kk) {
                sh8 bb = *(const sh8*)(w1 + n*C_ + kk*32 + l4*8);
                acc = __builtin_amdgcn_mfma_f32_16x16x32_bf16(a1[kk], bb, acc, 0,0,0);
            }
            float bias = f1b[n];
            #pragma unroll
            for (int r = 0; r < 4; ++r) {
                float xv = acc[r] + bias;
                float g = xv * 0.5f * (1.f + erff(xv * 0.70710678118654752f));
                int m = mt*16 + l4*4 + r;
                hv[m*520 + n] = f2bs(g);
            }
        }
    }
    __syncthreads();

    {
        int mt = wv & 1, ng = (wv >> 1) * 4;
        f32x4 acc[4] = {{0.f,0.f,0.f,0.f},{0.f,0.f,0.f,0.f},{0.f,0.f,0.f,0.f},{0.f,0.f,0.f,0.f}};
        for (int kk = 0; kk < 16; ++kk) {
            sh8 av = *(const sh8*)(hv + (mt*16 + l15)*520 + kk*32 + l4*8);
            #pragma unroll
            for (int t = 0; t < 4; ++t) {
                sh8 bb = *(const sh8*)(w2 + ((ng + t)*16 + l15)*512 + kk*32 + l4*8);
                acc[t] = __builtin_amdgcn_mfma_f32_16x16x32_bf16(av, bb, acc[t], 0,0,0);
            }
        }
        #pragma unroll
        for (int t = 0; t < 4; ++t) {
            int ch = (ng + t)*16 + l15;
            float bias = f2b[ch];
            #pragma unroll
            for (int r = 0; r < 4; ++r) {
                int m = mt*16 + l4*4 + r;
                xio[base + m*C_ + ch] = xin[m*C_ + ch] + acc[t][r] + bias;
            }
        }
    }
}

extern "C" void kernel_launch(void* const* d_in, const int* in_sizes, int n_in,
                              void* d_out, int out_size, void* d_ws, size_t ws_size,
                              hipStream_t stream) {
    const float* x    = (const float*)d_in[0];
    const float* n1g  = (const float*)d_in[1];
    const float* n1b  = (const float*)d_in[2];
    const float* qkvw = (const float*)d_in[3];
    const float* qkvb = (const float*)d_in[4];
    const float* rpb  = (const float*)d_in[5];
    const float* pw   = (const float*)d_in[6];
    const float* pb   = (const float*)d_in[7];
    const float* n2g  = (const float*)d_in[8];
    const float* n2b  = (const float*)d_in[9];
    const float* f1w  = (const float*)d_in[10];
    const float* f1b  = (const float*)d_in[11];
    const float* f2w  = (const float*)d_in[12];
    const float* f2b  = (const float*)d_in[13];

    short* ws = (short*)d_ws;          // bf16 transposed weights
    const short* wq = ws;
    const short* wp = ws + 49152;
    const short* w1 = ws + 65536;
    const short* w2 = ws + 131072;
    float* xio = (float*)d_out;

    hipLaunchKernelGGL(prep_k, dim3(768), dim3(256), 0, stream, qkvw, pw, f1w, f2w, ws);
    hipLaunchKernelGGL(win_attn, dim3(B_*NWIN_), dim3(256), 0, stream,
                       x, n1g, n1b, qkvb, rpb, pb, wq, wp, xio);
    hipLaunchKernelGGL(mlp_k, dim3(B_*H1_*W1_/32), dim3(256), 0, stream,
                       xio, n2g, n2b, f1b, f2b, w1, w2);
}